// Round 6
// baseline (434.022 us; speedup 1.0000x reference)
//
#include <hip/hip_runtime.h>
#include <hip/hip_fp16.h>
#include <cmath>

#define NN 50000
#define NE 800000
#define HIDDEN_C 128
#define NPB 32
#define NBKT 98        // ceil(50000/512)
#define BKT_SHIFT 9    // 512 nodes per bucket
#define BKT_NODES 512
#define CHUNK 8192
#define NCH 98         // ceil(800000/8192)
#define NPASS 4        // feature col-blocks of 32 cols (16 half2) each

__device__ __forceinline__ float sigmoidf_(float x) {
    return 1.0f / (1.0f + __expf(-x));
}
__device__ __forceinline__ float tanhf_(float x) {
    float t = __expf(-2.0f * fabsf(x));
    float r = (1.0f - t) / (1.0f + t);
    return copysignf(r, x);
}

// ---------------- prep: feat f32 -> col-blocked fp16, W^T, degree hist ----
// feat_q layout: [cb][node][16 half2]  (cb = col/32), region stride NN*16 half2
__global__ __launch_bounds__(256) void prep_kernel(
    const float* __restrict__ feat, __half2* __restrict__ fq,
    const float* __restrict__ Wih, const float* __restrict__ Whh,
    float* __restrict__ WTih, float* __restrict__ WThh,
    const int* __restrict__ dst0, const int* __restrict__ dst1,
    int* __restrict__ deg0, int* __restrict__ deg1) {
    int i = blockIdx.x * blockDim.x + threadIdx.x;  // 0 .. 1,599,999

    {
        const float4 v = ((const float4*)feat)[i];
        int n  = i >> 5;          // node
        int f4 = i & 31;          // which float4 in the row
        int cb = f4 >> 3;         // col-block
        int w  = f4 & 7;          // float4 within block (-> 2 half2)
        __half2* dst_q = fq + (size_t)cb * NN * 16 + (size_t)n * 16 + 2 * w;
        dst_q[0] = __floats2half2_rn(v.x, v.y);
        dst_q[1] = __floats2half2_rn(v.z, v.w);
    }
    if (i < NE) {
        atomicAdd(&deg0[dst0[i]], 1);
        atomicAdd(&deg1[dst1[i]], 1);
    }
    if (i < 256 * 128) {
        int g = i >> 7, k = i & 127;
        WTih[k * 256 + g] = Wih[i];
    }
    if (i < 256 * 64) {
        int g = i >> 6, k = i & 63;
        WThh[k * 256 + g] = Whh[i];
    }
}

// ---------------- bucket totals + range reservation (order-free) --------
__global__ __launch_bounds__(64) void bucket_sum_kernel(
    const int* __restrict__ deg0, const int* __restrict__ deg1,
    int* __restrict__ boff, int* __restrict__ bcur, int* __restrict__ bcnt,
    int* __restrict__ ctrs) {
    int g   = blockIdx.x;            // 0 .. 2*NBKT-1
    int et  = g >= NBKT;
    int b   = et ? g - NBKT : g;
    int lane = threadIdx.x;
    const int* deg = et ? deg1 : deg0;
    int node0 = b * BKT_NODES;
    int s = 0;
#pragma unroll
    for (int j = 0; j < 8; j++) {
        int idx = node0 + lane + j * 64;
        if (idx < NN) s += deg[idx];
    }
    for (int o = 32; o > 0; o >>= 1) s += __shfl_down(s, o, 64);
    if (lane == 0) {
        int o = atomicAdd(&ctrs[et], s);
        boff[g] = o;
        bcur[g] = o;
        bcnt[g] = s;
    }
}

// ---------------- phase A: bin edges into bucket-contiguous runs --------
__global__ __launch_bounds__(256) void bin_kernel(
    const int* __restrict__ src0, const int* __restrict__ dst0,
    const int* __restrict__ src1, const int* __restrict__ dst1,
    int* __restrict__ bcur,
    unsigned* __restrict__ binned0, unsigned* __restrict__ binned1) {
    __shared__ int cnt[NBKT];
    __shared__ int base[NBKT];
    __shared__ int cur[NBKT];

    int x  = blockIdx.x;             // 0 .. 2*NCH-1
    int et = x >= NCH;
    int c  = et ? x - NCH : x;
    const int* src = et ? src1 : src0;
    const int* dst = et ? dst1 : dst0;
    unsigned* binned = et ? binned1 : binned0;

    int start = c * CHUNK;
    int n = min(CHUNK, NE - start);
    int tid = threadIdx.x;

    if (tid < NBKT) { cnt[tid] = 0; cur[tid] = 0; }
    __syncthreads();
    for (int i = tid; i < n; i += 256) {
        int b = dst[start + i] >> BKT_SHIFT;
        atomicAdd(&cnt[b], 1);
    }
    __syncthreads();
    if (tid < NBKT && cnt[tid] > 0)
        base[tid] = atomicAdd(&bcur[et * NBKT + tid], cnt[tid]);
    __syncthreads();
    for (int i = tid; i < n; i += 256) {
        int d = dst[start + i];
        int b = d >> BKT_SHIFT;
        int r = atomicAdd(&cur[b], 1);
        binned[base[b] + r] = ((unsigned)d << 16) | (unsigned)src[start + i];
    }
}

// ---------------- phase B: per-bucket CSR finalize + es scatter ---------
__global__ __launch_bounds__(256) void bucket_scatter_kernel(
    const unsigned* __restrict__ binned0, const unsigned* __restrict__ binned1,
    const int* __restrict__ boff, const int* __restrict__ bcnt,
    int* __restrict__ off0, int* __restrict__ off1,
    unsigned short* __restrict__ es0, unsigned short* __restrict__ es1) {
    __shared__ int lcnt[BKT_NODES];
    __shared__ int lbase[BKT_NODES];

    int g  = blockIdx.x;             // 0 .. 2*NBKT-1
    int et = g >= NBKT;
    int b  = et ? g - NBKT : g;
    const unsigned* binned = et ? binned1 : binned0;
    int* off = et ? off1 : off0;
    unsigned short* es = et ? es1 : es0;

    int bo = boff[g];
    int bn = bcnt[g];
    int node0 = b * BKT_NODES;
    int tid = threadIdx.x;

    lcnt[tid] = 0;
    lcnt[tid + 256] = 0;
    __syncthreads();
    for (int i = tid; i < bn; i += 256) {
        unsigned u = binned[bo + i];
        int d = (int)(u >> 16) - node0;
        atomicAdd(&lcnt[d], 1);
    }
    __syncthreads();
    int o0 = lcnt[tid], o1 = lcnt[tid + 256];
    for (int d = 1; d < BKT_NODES; d <<= 1) {
        int v0 = (tid >= d) ? lcnt[tid - d] : 0;
        int v1 = (tid + 256 >= d) ? lcnt[tid + 256 - d] : 0;
        __syncthreads();
        lcnt[tid] += v0;
        lcnt[tid + 256] += v1;
        __syncthreads();
    }
    int e0 = lcnt[tid] - o0;
    int e1 = lcnt[tid + 256] - o1;
    lbase[tid] = e0;
    lbase[tid + 256] = e1;
    int gn0 = node0 + tid, gn1 = node0 + tid + 256;
    if (gn0 < NN) off[gn0] = bo + e0;
    if (gn1 < NN) off[gn1] = bo + e1;
    __syncthreads();
    for (int i = tid; i < bn; i += 256) {
        unsigned u = binned[bo + i];
        int d = (int)(u >> 16) - node0;
        int r = atomicAdd(&lbase[d], 1);
        es[bo + r] = (unsigned short)(u & 0xffffu);
    }
}

// ---------------- gather pass: 32 cols, table L2-resident ---------------
// wave = 1 node; 4 sub-groups of 16 lanes each process one edge/iter;
// lane (sub, c) loads fq[src*16 + c] (64 B per edge). Final shfl_xor combine.
__global__ __launch_bounds__(256) void gather_pass_kernel(
    const __half2* __restrict__ fq,   // this pass's 3.2 MB region
    const unsigned short* __restrict__ es0, const int* __restrict__ off0, const int* __restrict__ deg0,
    const unsigned short* __restrict__ es1, const int* __restrict__ off1, const int* __restrict__ deg1,
    __half2* __restrict__ rst2, int cb) {
    int wid  = (blockIdx.x * blockDim.x + threadIdx.x) >> 6;
    if (wid >= NN) return;
    int lane = threadIdx.x & 63;
    int sub  = lane >> 4;    // 0..3: which edge of the quad
    int c    = lane & 15;    // half2 col within the 32-col block

    float ax0 = 0.f, ay0 = 0.f, ax1 = 0.f, ay1 = 0.f;

    int d0 = deg0[wid], o0 = off0[wid];
    for (int eb = 0; eb < d0; eb += 4) {
        int e = eb + sub;
        bool val = e < d0;
        int s = val ? (int)__builtin_nontemporal_load(&es0[o0 + e]) : 0;
        float2 v = __half22float2(fq[(size_t)s * 16 + c]);
        float m = val ? 1.f : 0.f;
        ax0 = fmaf(v.x, m, ax0);
        ay0 = fmaf(v.y, m, ay0);
    }
    int d1 = deg1[wid], o1 = off1[wid];
    for (int eb = 0; eb < d1; eb += 4) {
        int e = eb + sub;
        bool val = e < d1;
        int s = val ? (int)__builtin_nontemporal_load(&es1[o1 + e]) : 0;
        float2 v = __half22float2(fq[(size_t)s * 16 + c]);
        float m = val ? 1.f : 0.f;
        ax1 = fmaf(v.x, m, ax1);
        ay1 = fmaf(v.y, m, ay1);
    }

    // combine the 4 sub-group partials (lanes differing in bits 4,5)
    ax0 += __shfl_xor(ax0, 16, 64); ax0 += __shfl_xor(ax0, 32, 64);
    ay0 += __shfl_xor(ay0, 16, 64); ay0 += __shfl_xor(ay0, 32, 64);
    ax1 += __shfl_xor(ax1, 16, 64); ax1 += __shfl_xor(ax1, 32, 64);
    ay1 += __shfl_xor(ay1, 16, 64); ay1 += __shfl_xor(ay1, 32, 64);

    if (sub == 0) {
        float inv0 = 1.0f / fmaxf((float)d0, 1.0f);
        float inv1 = 1.0f / fmaxf((float)d1, 1.0f);
        float na = fmaxf((float)((d0 > 0) + (d1 > 0)), 1.0f);
        float rx = (ax0 * inv0 + ax1 * inv1) / na;
        float ry = (ay0 * inv0 + ay1 * inv1) / na;
        rst2[(size_t)wid * 64 + cb * 16 + c] = __floats2half2_rn(rx, ry);
    }
}

// ---------------- node kernel: gates GEMM + LSTM epilogue ---------------
__global__ __launch_bounds__(256) void node_kernel(
    const __half2* __restrict__ fq,      // col-blocked feat
    const __half2* __restrict__ rst2h,   // row-major rst
    const float* __restrict__ WTih, const float* __restrict__ WThh,
    const float* __restrict__ b_ih, const float* __restrict__ b_hh,
    float* __restrict__ out) {
    __shared__ float feat_s[NPB][HIDDEN_C];
    __shared__ float rst_s[NPB][HIDDEN_C];

    int t  = threadIdx.x;
    int nb = blockIdx.x * NPB;

    for (int idx = t; idx < NPB * 64; idx += 256) {
        int n = idx >> 6, k2 = idx & 63;
        int gn = nb + n;
        int cb = k2 >> 4, w = k2 & 15;
        float2 fv = make_float2(0.f, 0.f), rv = make_float2(0.f, 0.f);
        if (gn < NN) {
            fv = __half22float2(fq[(size_t)cb * NN * 16 + (size_t)gn * 16 + w]);
            rv = __half22float2(rst2h[(size_t)gn * 64 + k2]);
        }
        feat_s[n][cb * 32 + 2 * w]     = fv.x;
        feat_s[n][cb * 32 + 2 * w + 1] = fv.y;
        rst_s[n][2 * k2]      = rv.x;
        rst_s[n][2 * k2 + 1]  = rv.y;
    }
    __syncthreads();

    int lane = t & 63;
    int wv   = t >> 6;

    float bias[4];
#pragma unroll
    for (int c = 0; c < 4; c++) bias[c] = b_ih[c * 64 + lane] + b_hh[c * 64 + lane];

    float acc[8][4];
#pragma unroll
    for (int it = 0; it < 8; it++)
#pragma unroll
        for (int c = 0; c < 4; c++) acc[it][c] = bias[c];

    for (int k = 0; k < 128; k++) {
        float w0 = WTih[k * 256 + 0 * 64 + lane];
        float w1 = WTih[k * 256 + 1 * 64 + lane];
        float w2 = WTih[k * 256 + 2 * 64 + lane];
        float w3 = WTih[k * 256 + 3 * 64 + lane];
#pragma unroll
        for (int it = 0; it < 8; it++) {
            float fv = feat_s[wv + 4 * it][k];
            acc[it][0] = fmaf(fv, w0, acc[it][0]);
            acc[it][1] = fmaf(fv, w1, acc[it][1]);
            acc[it][2] = fmaf(fv, w2, acc[it][2]);
            acc[it][3] = fmaf(fv, w3, acc[it][3]);
        }
    }
    for (int k = 0; k < 64; k++) {
        float w0 = WThh[k * 256 + 0 * 64 + lane];
        float w1 = WThh[k * 256 + 1 * 64 + lane];
        float w2 = WThh[k * 256 + 2 * 64 + lane];
        float w3 = WThh[k * 256 + 3 * 64 + lane];
#pragma unroll
        for (int it = 0; it < 8; it++) {
            float gv = rst_s[wv + 4 * it][k];
            acc[it][0] = fmaf(gv, w0, acc[it][0]);
            acc[it][1] = fmaf(gv, w1, acc[it][1]);
            acc[it][2] = fmaf(gv, w2, acc[it][2]);
            acc[it][3] = fmaf(gv, w3, acc[it][3]);
        }
    }

#pragma unroll
    for (int it = 0; it < 8; it++) {
        int n  = wv + 4 * it;
        int gn = nb + n;
        if (gn >= NN) continue;
        float R  = rst_s[n][64 + lane];
        float iv = sigmoidf_(acc[it][0]);
        float fv = sigmoidf_(acc[it][1]);
        float gv = tanhf_(acc[it][2]);
        float ov = sigmoidf_(acc[it][3]);
        float c1 = fv * R + iv * gv;
        float h1 = ov * tanhf_(c1);
        out[(long)gn * 128 + lane]      = h1;
        out[(long)gn * 128 + 64 + lane] = c1;
    }
}

extern "C" void kernel_launch(void* const* d_in, const int* in_sizes, int n_in,
                              void* d_out, int out_size, void* d_ws, size_t ws_size,
                              hipStream_t stream) {
    const float* feat = (const float*)d_in[0];
    const int*   src0 = (const int*)d_in[1];
    const int*   dst0 = (const int*)d_in[2];
    const int*   src1 = (const int*)d_in[3];
    const int*   dst1 = (const int*)d_in[4];
    const float* W_ih = (const float*)d_in[5];
    const float* W_hh = (const float*)d_in[6];
    const float* b_ih = (const float*)d_in[7];
    const float* b_hh = (const float*)d_in[8];
    float* out = (float*)d_out;

    // workspace layout
    char* p = (char*)d_ws;
    int* deg0 = (int*)p;            p += NN * 4;         // zeroed
    int* deg1 = (int*)p;            p += NN * 4;         // zeroed
    int* ctrs = (int*)p;            p += 4 * 4;          // zeroed (2 used)
    int* boff = (int*)p;            p += 2 * NBKT * 4;
    int* bcur = (int*)p;            p += 2 * NBKT * 4;
    int* bcnt = (int*)p;            p += 2 * NBKT * 4;
    int* off0 = (int*)p;            p += NN * 4;
    int* off1 = (int*)p;            p += NN * 4;
    unsigned* binned0 = (unsigned*)p; p += (size_t)NE * 4;
    unsigned* binned1 = (unsigned*)p; p += (size_t)NE * 4;
    unsigned short* es0 = (unsigned short*)p; p += (size_t)NE * 2;
    unsigned short* es1 = (unsigned short*)p; p += (size_t)NE * 2;
    __half2* fq   = (__half2*)p;    p += (size_t)NPASS * NN * 16 * 4;  // 12.8 MB
    __half2* rst2 = (__half2*)p;    p += (size_t)NN * 64 * 4;          // 12.8 MB
    float* WTih = (float*)p;        p += 256 * 128 * 4;
    float* WThh = (float*)p;        p += 256 * 64 * 4;

    hipMemsetAsync(deg0, 0, (2 * NN + 4) * sizeof(int), stream);

    int blocksP = (NN * 128 / 4 + 255) / 256;  // 6250
    prep_kernel<<<blocksP, 256, 0, stream>>>(feat, fq, W_ih, W_hh, WTih, WThh,
                                             dst0, dst1, deg0, deg1);

    bucket_sum_kernel<<<2 * NBKT, 64, 0, stream>>>(deg0, deg1, boff, bcur, bcnt, ctrs);

    bin_kernel<<<2 * NCH, 256, 0, stream>>>(src0, dst0, src1, dst1, bcur, binned0, binned1);

    bucket_scatter_kernel<<<2 * NBKT, 256, 0, stream>>>(binned0, binned1, boff, bcnt,
                                                        off0, off1, es0, es1);

    int blocksG = (NN * 64 + 255) / 256;  // 12500 (one wave per node)
    for (int cb = 0; cb < NPASS; cb++) {
        gather_pass_kernel<<<blocksG, 256, 0, stream>>>(
            fq + (size_t)cb * NN * 16,
            es0, off0, deg0, es1, off1, deg1,
            rst2, cb);
    }

    int blocksN = (NN + NPB - 1) / NPB;   // 1563
    node_kernel<<<blocksN, 256, 0, stream>>>(fq, rst2, WTih, WThh, b_ih, b_hh, out);
}

// Round 7
// 255.883 us; speedup vs baseline: 1.6962x; 1.6962x over previous
//
#include <hip/hip_runtime.h>
#include <hip/hip_fp16.h>
#include <cmath>

#define NN 50000
#define NE 800000
#define HIDDEN_C 128
#define NPB 32
#define NBKT 98        // ceil(50000/512)
#define BKT_SHIFT 9    // 512 nodes per bucket
#define BKT_NODES 512
#define CHUNK 8192
#define NCH 98         // ceil(800000/8192)

using f16x8 = __attribute__((ext_vector_type(8))) _Float16;
using f32x4 = __attribute__((ext_vector_type(4))) float;

__device__ __forceinline__ float sigmoidf_(float x) {
    return 1.0f / (1.0f + __expf(-x));
}
__device__ __forceinline__ float tanhf_(float x) {
    float t = __expf(-2.0f * fabsf(x));
    float r = (1.0f - t) / (1.0f + t);
    return copysignf(r, x);
}

// ---------------- prep: feat f32->f16 row-major, WC fp16, bias, hist ----
__global__ __launch_bounds__(256) void prep_kernel(
    const float* __restrict__ feat, __half* __restrict__ feat_h,
    const float* __restrict__ Wih, const float* __restrict__ Whh,
    const float* __restrict__ b_ih, const float* __restrict__ b_hh,
    __half* __restrict__ WC, float* __restrict__ bsum,
    const int* __restrict__ dst0, const int* __restrict__ dst1,
    int* __restrict__ deg0, int* __restrict__ deg1) {
    int i = blockIdx.x * blockDim.x + threadIdx.x;  // 0 .. 1,599,999

    {
        const float4 v = ((const float4*)feat)[i];
        __half2 lo = __floats2half2_rn(v.x, v.y);
        __half2 hi = __floats2half2_rn(v.z, v.w);
        ((__half2*)feat_h)[2 * i]     = lo;
        ((__half2*)feat_h)[2 * i + 1] = hi;
    }
    if (i < NE) {
        atomicAdd(&deg0[dst0[i]], 1);
        atomicAdd(&deg1[dst1[i]], 1);
    }
    // WC[g][0:128] = W_ih[g][:], WC[g][128:192] = W_hh[g][:]
    if (i < 256 * 128) {
        int g = i >> 7, k = i & 127;
        WC[(size_t)g * 192 + k] = __float2half(Wih[i]);
    }
    if (i < 256 * 64) {
        int g = i >> 6, k = i & 63;
        WC[(size_t)g * 192 + 128 + k] = __float2half(Whh[i]);
    }
    if (i < 256) bsum[i] = b_ih[i] + b_hh[i];
}

// ---------------- bucket totals + range reservation (order-free) --------
__global__ __launch_bounds__(64) void bucket_sum_kernel(
    const int* __restrict__ deg0, const int* __restrict__ deg1,
    int* __restrict__ boff, int* __restrict__ bcur, int* __restrict__ bcnt,
    int* __restrict__ ctrs) {
    int g   = blockIdx.x;            // 0 .. 2*NBKT-1
    int et  = g >= NBKT;
    int b   = et ? g - NBKT : g;
    int lane = threadIdx.x;
    const int* deg = et ? deg1 : deg0;
    int node0 = b * BKT_NODES;
    int s = 0;
#pragma unroll
    for (int j = 0; j < 8; j++) {
        int idx = node0 + lane + j * 64;
        if (idx < NN) s += deg[idx];
    }
    for (int o = 32; o > 0; o >>= 1) s += __shfl_down(s, o, 64);
    if (lane == 0) {
        int o = atomicAdd(&ctrs[et], s);
        boff[g] = o;
        bcur[g] = o;
        bcnt[g] = s;
    }
}

// ---------------- phase A: bin edges into bucket-contiguous runs --------
__global__ __launch_bounds__(256) void bin_kernel(
    const int* __restrict__ src0, const int* __restrict__ dst0,
    const int* __restrict__ src1, const int* __restrict__ dst1,
    int* __restrict__ bcur,
    unsigned* __restrict__ binned0, unsigned* __restrict__ binned1) {
    __shared__ int cnt[NBKT];
    __shared__ int base[NBKT];
    __shared__ int cur[NBKT];

    int x  = blockIdx.x;             // 0 .. 2*NCH-1
    int et = x >= NCH;
    int c  = et ? x - NCH : x;
    const int* src = et ? src1 : src0;
    const int* dst = et ? dst1 : dst0;
    unsigned* binned = et ? binned1 : binned0;

    int start = c * CHUNK;
    int n = min(CHUNK, NE - start);
    int tid = threadIdx.x;

    if (tid < NBKT) { cnt[tid] = 0; cur[tid] = 0; }
    __syncthreads();
    for (int i = tid; i < n; i += 256) {
        int b = dst[start + i] >> BKT_SHIFT;
        atomicAdd(&cnt[b], 1);
    }
    __syncthreads();
    if (tid < NBKT && cnt[tid] > 0)
        base[tid] = atomicAdd(&bcur[et * NBKT + tid], cnt[tid]);
    __syncthreads();
    for (int i = tid; i < n; i += 256) {
        int d = dst[start + i];
        int b = d >> BKT_SHIFT;
        int r = atomicAdd(&cur[b], 1);
        binned[base[b] + r] = ((unsigned)d << 16) | (unsigned)src[start + i];
    }
}

// ---------------- phase B: per-bucket CSR finalize + es scatter ---------
__global__ __launch_bounds__(256) void bucket_scatter_kernel(
    const unsigned* __restrict__ binned0, const unsigned* __restrict__ binned1,
    const int* __restrict__ boff, const int* __restrict__ bcnt,
    int* __restrict__ off0, int* __restrict__ off1,
    unsigned short* __restrict__ es0, unsigned short* __restrict__ es1) {
    __shared__ int lcnt[BKT_NODES];
    __shared__ int lbase[BKT_NODES];

    int g  = blockIdx.x;             // 0 .. 2*NBKT-1
    int et = g >= NBKT;
    int b  = et ? g - NBKT : g;
    const unsigned* binned = et ? binned1 : binned0;
    int* off = et ? off1 : off0;
    unsigned short* es = et ? es1 : es0;

    int bo = boff[g];
    int bn = bcnt[g];
    int node0 = b * BKT_NODES;
    int tid = threadIdx.x;

    lcnt[tid] = 0;
    lcnt[tid + 256] = 0;
    __syncthreads();
    for (int i = tid; i < bn; i += 256) {
        unsigned u = binned[bo + i];
        int d = (int)(u >> 16) - node0;
        atomicAdd(&lcnt[d], 1);
    }
    __syncthreads();
    int o0 = lcnt[tid], o1 = lcnt[tid + 256];
    for (int d = 1; d < BKT_NODES; d <<= 1) {
        int v0 = (tid >= d) ? lcnt[tid - d] : 0;
        int v1 = (tid + 256 >= d) ? lcnt[tid + 256 - d] : 0;
        __syncthreads();
        lcnt[tid] += v0;
        lcnt[tid + 256] += v1;
        __syncthreads();
    }
    int e0 = lcnt[tid] - o0;
    int e1 = lcnt[tid + 256] - o1;
    lbase[tid] = e0;
    lbase[tid + 256] = e1;
    int gn0 = node0 + tid, gn1 = node0 + tid + 256;
    if (gn0 < NN) off[gn0] = bo + e0;
    if (gn1 < NN) off[gn1] = bo + e1;
    __syncthreads();
    for (int i = tid; i < bn; i += 256) {
        unsigned u = binned[bo + i];
        int d = (int)(u >> 16) - node0;
        int r = atomicAdd(&lbase[d], 1);
        es[bo + r] = (unsigned short)(u & 0xffffu);
    }
}

// ---------------- gather: one wave per node, half2 per lane (round-5) ---
__global__ __launch_bounds__(256) void gather_kernel(
    const __half2* __restrict__ feat2,
    const unsigned short* __restrict__ es0, const int* __restrict__ off0, const int* __restrict__ deg0,
    const unsigned short* __restrict__ es1, const int* __restrict__ off1, const int* __restrict__ deg1,
    __half2* __restrict__ rst2) {
    int wid  = (blockIdx.x * blockDim.x + threadIdx.x) >> 6;
    int lane = threadIdx.x & 63;
    if (wid >= NN) return;

    float ax0 = 0.f, ay0 = 0.f, ax1 = 0.f, ay1 = 0.f;
    int d0 = deg0[wid], o0 = off0[wid];
    int e = 0;
    for (; e + 2 <= d0; e += 2) {
        int s0 = es0[o0 + e];
        int s1 = es0[o0 + e + 1];
        float2 v0 = __half22float2(feat2[(long)s0 * 64 + lane]);
        float2 v1 = __half22float2(feat2[(long)s1 * 64 + lane]);
        ax0 += v0.x; ay0 += v0.y;
        ax0 += v1.x; ay0 += v1.y;
    }
    if (e < d0) {
        int s0 = es0[o0 + e];
        float2 v0 = __half22float2(feat2[(long)s0 * 64 + lane]);
        ax0 += v0.x; ay0 += v0.y;
    }
    int d1 = deg1[wid], o1 = off1[wid];
    e = 0;
    for (; e + 2 <= d1; e += 2) {
        int s0 = es1[o1 + e];
        int s1 = es1[o1 + e + 1];
        float2 v0 = __half22float2(feat2[(long)s0 * 64 + lane]);
        float2 v1 = __half22float2(feat2[(long)s1 * 64 + lane]);
        ax1 += v0.x; ay1 += v0.y;
        ax1 += v1.x; ay1 += v1.y;
    }
    if (e < d1) {
        int s0 = es1[o1 + e];
        float2 v0 = __half22float2(feat2[(long)s0 * 64 + lane]);
        ax1 += v0.x; ay1 += v0.y;
    }
    float inv0 = 1.0f / fmaxf((float)d0, 1.0f);
    float inv1 = 1.0f / fmaxf((float)d1, 1.0f);
    float na = fmaxf((float)((d0 > 0) + (d1 > 0)), 1.0f);
    float rx = (ax0 * inv0 + ax1 * inv1) / na;
    float ry = (ay0 * inv0 + ay1 * inv1) / na;
    rst2[(long)wid * 64 + lane] = __floats2half2_rn(rx, ry);
}

// ---------------- node kernel: MFMA gates GEMM + LSTM epilogue ----------
// block = 32 nodes, 4 waves. X = [feat | G] (K=192) in LDS, stride 200 halves.
// Wave w owns hidden units m in [w*16, w*16+16); col-tile ct = gate block
// (i,f,g,o) at gate = ct*64 + w*16 + col -> epilogue is register-local.
__global__ __launch_bounds__(256) void node_kernel(
    const __half* __restrict__ feat_h,
    const __half* __restrict__ rst_h,
    const __half* __restrict__ WC, const float* __restrict__ bsum,
    float* __restrict__ out) {
    __shared__ __half xs[32 * 200];

    int t  = threadIdx.x;
    int nb = blockIdx.x * NPB;
    int lane = t & 63;
    int w    = t >> 6;
    int col  = lane & 15;   // A-row / C-col / B-col
    int g4   = lane >> 4;   // k-group

    // B fragments (shared weights, L2-broadcast) + bias — independent of LDS
    f16x8 bfr[4][6];
    float bias[4];
#pragma unroll
    for (int ct = 0; ct < 4; ct++) {
        int gate = ct * 64 + w * 16 + col;
        bias[ct] = bsum[gate];
#pragma unroll
        for (int ks = 0; ks < 6; ks++)
            bfr[ct][ks] = *(const f16x8*)(WC + (size_t)gate * 192 + ks * 32 + g4 * 8);
    }

    // stage X = [feat(128) | G(64)] for 32 nodes
    const uint4* feat4 = (const uint4*)feat_h;   // 16 uint4 per node row
    const uint4* rst4  = (const uint4*)rst_h;
#pragma unroll
    for (int j = 0; j < 2; j++) {
        int e = t + j * 256;          // 0..511
        int n = e >> 4, q = e & 15;
        int gn = nb + n;
        uint4 v = make_uint4(0, 0, 0, 0);
        if (gn < NN) v = feat4[(size_t)gn * 16 + q];
        *(uint4*)(&xs[n * 200 + q * 8]) = v;
    }
    {
        int n = t >> 3, q = t & 7;    // G = first 8 uint4 of rst row
        int gn = nb + n;
        uint4 v = make_uint4(0, 0, 0, 0);
        if (gn < NN) v = rst4[(size_t)gn * 16 + q];
        *(uint4*)(&xs[n * 200 + 128 + q * 8]) = v;
    }
    __syncthreads();

    f32x4 acc[2][4];
#pragma unroll
    for (int rt = 0; rt < 2; rt++)
#pragma unroll
        for (int ct = 0; ct < 4; ct++)
            acc[rt][ct] = (f32x4){bias[ct], bias[ct], bias[ct], bias[ct]};

#pragma unroll
    for (int ks = 0; ks < 6; ks++) {
        f16x8 a0 = *(const f16x8*)(&xs[(col) * 200 + ks * 32 + g4 * 8]);
        f16x8 a1 = *(const f16x8*)(&xs[(16 + col) * 200 + ks * 32 + g4 * 8]);
#pragma unroll
        for (int ct = 0; ct < 4; ct++) {
            acc[0][ct] = __builtin_amdgcn_mfma_f32_16x16x32_f16(a0, bfr[ct][ks], acc[0][ct], 0, 0, 0);
            acc[1][ct] = __builtin_amdgcn_mfma_f32_16x16x32_f16(a1, bfr[ct][ks], acc[1][ct], 0, 0, 0);
        }
    }

    // epilogue: C/D layout col=lane&15 (gate), row=(lane>>4)*4+reg (node)
    int m = w * 16 + col;
#pragma unroll
    for (int rt = 0; rt < 2; rt++) {
#pragma unroll
        for (int r = 0; r < 4; r++) {
            int nl = rt * 16 + g4 * 4 + r;
            int gn = nb + nl;
            if (gn >= NN) continue;
            float iv = sigmoidf_(acc[rt][0][r]);
            float fv = sigmoidf_(acc[rt][1][r]);
            float gv = tanhf_(acc[rt][2][r]);
            float ov = sigmoidf_(acc[rt][3][r]);
            float R  = __half2float(rst_h[(size_t)gn * 128 + 64 + m]);
            float c1 = fv * R + iv * gv;
            float h1 = ov * tanhf_(c1);
            out[(size_t)gn * 128 + m]      = h1;
            out[(size_t)gn * 128 + 64 + m] = c1;
        }
    }
}

extern "C" void kernel_launch(void* const* d_in, const int* in_sizes, int n_in,
                              void* d_out, int out_size, void* d_ws, size_t ws_size,
                              hipStream_t stream) {
    const float* feat = (const float*)d_in[0];
    const int*   src0 = (const int*)d_in[1];
    const int*   dst0 = (const int*)d_in[2];
    const int*   src1 = (const int*)d_in[3];
    const int*   dst1 = (const int*)d_in[4];
    const float* W_ih = (const float*)d_in[5];
    const float* W_hh = (const float*)d_in[6];
    const float* b_ih = (const float*)d_in[7];
    const float* b_hh = (const float*)d_in[8];
    float* out = (float*)d_out;

    // workspace layout (all 16B-aligned)
    char* p = (char*)d_ws;
    int* deg0 = (int*)p;            p += NN * 4;         // zeroed
    int* deg1 = (int*)p;            p += NN * 4;         // zeroed
    int* ctrs = (int*)p;            p += 4 * 4;          // zeroed (2 used)
    int* boff = (int*)p;            p += 2 * NBKT * 4;
    int* bcur = (int*)p;            p += 2 * NBKT * 4;
    int* bcnt = (int*)p;            p += 2 * NBKT * 4;
    int* off0 = (int*)p;            p += NN * 4;
    int* off1 = (int*)p;            p += NN * 4;
    unsigned* binned0 = (unsigned*)p; p += (size_t)NE * 4;
    unsigned* binned1 = (unsigned*)p; p += (size_t)NE * 4;
    unsigned short* es0 = (unsigned short*)p; p += (size_t)NE * 2;
    unsigned short* es1 = (unsigned short*)p; p += (size_t)NE * 2;
    __half* feat_h = (__half*)p;    p += (size_t)NN * 128 * 2;
    __half* rst_h  = (__half*)p;    p += (size_t)NN * 128 * 2;
    __half* WC     = (__half*)p;    p += (size_t)256 * 192 * 2;
    float*  bsum   = (float*)p;     p += 256 * 4;

    hipMemsetAsync(deg0, 0, (2 * NN + 4) * sizeof(int), stream);

    int blocksP = (NN * 128 / 4 + 255) / 256;  // 6250
    prep_kernel<<<blocksP, 256, 0, stream>>>(feat, feat_h, W_ih, W_hh, b_ih, b_hh,
                                             WC, bsum, dst0, dst1, deg0, deg1);

    bucket_sum_kernel<<<2 * NBKT, 64, 0, stream>>>(deg0, deg1, boff, bcur, bcnt, ctrs);

    bin_kernel<<<2 * NCH, 256, 0, stream>>>(src0, dst0, src1, dst1, bcur, binned0, binned1);

    bucket_scatter_kernel<<<2 * NBKT, 256, 0, stream>>>(binned0, binned1, boff, bcnt,
                                                        off0, off1, es0, es1);

    int blocksG = (NN * 64 + 255) / 256;  // 12500 (one wave per node)
    gather_kernel<<<blocksG, 256, 0, stream>>>((const __half2*)feat_h,
                                               es0, off0, deg0, es1, off1, deg1,
                                               (__half2*)rst_h);

    int blocksN = (NN + NPB - 1) / NPB;   // 1563
    node_kernel<<<blocksN, 256, 0, stream>>>(feat_h, rst_h, WC, bsum, out);
}

// Round 8
// 174.109 us; speedup vs baseline: 2.4928x; 1.4697x over previous
//
#include <hip/hip_runtime.h>
#include <hip/hip_fp16.h>
#include <cmath>

#define NN 50000
#define NE 800000
#define NPB 32
#define NBKT 98        // ceil(50000/512)
#define BKT_SHIFT 9    // 512 nodes per bucket
#define BKT_NODES 512
#define BKT_CAP 12288  // fixed region per bucket (mean 8192, sigma ~90)
#define CHUNK 8192
#define NCH 98         // ceil(800000/8192)

using f16x8 = __attribute__((ext_vector_type(8))) _Float16;
using f32x4 = __attribute__((ext_vector_type(4))) float;

__device__ __forceinline__ float sigmoidf_(float x) {
    return 1.0f / (1.0f + __expf(-x));
}
__device__ __forceinline__ float tanhf_(float x) {
    float t = __expf(-2.0f * fabsf(x));
    float r = (1.0f - t) / (1.0f + t);
    return copysignf(r, x);
}

// ---------------- prep: feat f32->f16, WC fp16, bias ----
__global__ __launch_bounds__(256) void prep_kernel(
    const float* __restrict__ feat, __half* __restrict__ feat_h,
    const float* __restrict__ Wih, const float* __restrict__ Whh,
    const float* __restrict__ b_ih, const float* __restrict__ b_hh,
    __half* __restrict__ WC, float* __restrict__ bsum) {
    int i = blockIdx.x * blockDim.x + threadIdx.x;  // 0 .. 1,599,999

    {
        const float4 v = ((const float4*)feat)[i];
        __half2 lo = __floats2half2_rn(v.x, v.y);
        __half2 hi = __floats2half2_rn(v.z, v.w);
        ((__half2*)feat_h)[2 * i]     = lo;
        ((__half2*)feat_h)[2 * i + 1] = hi;
    }
    // WC[g][0:128] = W_ih[g][:], WC[g][128:192] = W_hh[g][:]
    if (i < 256 * 128) {
        int g = i >> 7, k = i & 127;
        WC[(size_t)g * 192 + k] = __float2half(Wih[i]);
    }
    if (i < 256 * 64) {
        int g = i >> 6, k = i & 63;
        WC[(size_t)g * 192 + 128 + k] = __float2half(Whh[i]);
    }
    if (i < 256) bsum[i] = b_ih[i] + b_hh[i];
}

// ---------------- phase A: bin edges into fixed-stride bucket regions ---
// binned entry = (dst << 16) | src. Region for bucket b: [b*BKT_CAP, ...).
__global__ __launch_bounds__(256) void bin_kernel(
    const int* __restrict__ src0, const int* __restrict__ dst0,
    const int* __restrict__ src1, const int* __restrict__ dst1,
    int* __restrict__ bcnt,   // [2*NBKT], zeroed; doubles as bucket totals
    unsigned* __restrict__ binned0, unsigned* __restrict__ binned1) {
    __shared__ int cnt[NBKT];
    __shared__ int base[NBKT];
    __shared__ int cur[NBKT];

    int x  = blockIdx.x;             // 0 .. 2*NCH-1
    int et = x >= NCH;
    int c  = et ? x - NCH : x;
    const int* src = et ? src1 : src0;
    const int* dst = et ? dst1 : dst0;
    unsigned* binned = et ? binned1 : binned0;

    int start = c * CHUNK;
    int n = min(CHUNK, NE - start);
    int tid = threadIdx.x;

    if (tid < NBKT) { cnt[tid] = 0; cur[tid] = 0; }
    __syncthreads();
    for (int i = tid; i < n; i += 256) {
        int b = dst[start + i] >> BKT_SHIFT;
        atomicAdd(&cnt[b], 1);
    }
    __syncthreads();
    if (tid < NBKT && cnt[tid] > 0)
        base[tid] = atomicAdd(&bcnt[et * NBKT + tid], cnt[tid]);
    __syncthreads();
    for (int i = tid; i < n; i += 256) {
        int d = dst[start + i];
        int b = d >> BKT_SHIFT;
        int r = atomicAdd(&cur[b], 1);
        binned[(size_t)b * BKT_CAP + base[b] + r] =
            ((unsigned)d << 16) | (unsigned)src[start + i];
    }
}

// ---------------- phase B: per-bucket CSR finalize + es scatter ---------
// writes deg[] and off[] (off points into the bucket's fixed es region).
__global__ __launch_bounds__(256) void bucket_scatter_kernel(
    const unsigned* __restrict__ binned0, const unsigned* __restrict__ binned1,
    const int* __restrict__ bcnt,
    int* __restrict__ off0, int* __restrict__ off1,
    int* __restrict__ deg0, int* __restrict__ deg1,
    unsigned short* __restrict__ es0, unsigned short* __restrict__ es1) {
    __shared__ int lcnt[BKT_NODES];
    __shared__ int lbase[BKT_NODES];

    int g  = blockIdx.x;             // 0 .. 2*NBKT-1
    int et = g >= NBKT;
    int b  = et ? g - NBKT : g;
    const unsigned* binned = (et ? binned1 : binned0) + (size_t)b * BKT_CAP;
    int* off = et ? off1 : off0;
    int* deg = et ? deg1 : deg0;
    unsigned short* es = (et ? es1 : es0) + (size_t)b * BKT_CAP;

    int bn = bcnt[g];
    int node0 = b * BKT_NODES;
    int tid = threadIdx.x;

    lcnt[tid] = 0;
    lcnt[tid + 256] = 0;
    __syncthreads();
    for (int i = tid; i < bn; i += 256) {
        unsigned u = binned[i];
        int d = (int)(u >> 16) - node0;
        atomicAdd(&lcnt[d], 1);
    }
    __syncthreads();
    int o0 = lcnt[tid], o1 = lcnt[tid + 256];   // per-node counts
    for (int d = 1; d < BKT_NODES; d <<= 1) {
        int v0 = (tid >= d) ? lcnt[tid - d] : 0;
        int v1 = (tid + 256 >= d) ? lcnt[tid + 256 - d] : 0;
        __syncthreads();
        lcnt[tid] += v0;
        lcnt[tid + 256] += v1;
        __syncthreads();
    }
    int e0 = lcnt[tid] - o0;          // exclusive scan
    int e1 = lcnt[tid + 256] - o1;
    lbase[tid] = e0;
    lbase[tid + 256] = e1;
    int gn0 = node0 + tid, gn1 = node0 + tid + 256;
    if (gn0 < NN) { off[gn0] = b * BKT_CAP + e0; deg[gn0] = o0; }
    if (gn1 < NN) { off[gn1] = b * BKT_CAP + e1; deg[gn1] = o1; }
    __syncthreads();
    for (int i = tid; i < bn; i += 256) {
        unsigned u = binned[i];
        int d = (int)(u >> 16) - node0;
        int r = atomicAdd(&lbase[d], 1);
        es[r] = (unsigned short)(u & 0xffffu);
    }
}

// ---------------- gather: one wave per node, 4 row-loads in flight ------
__global__ __launch_bounds__(256) void gather_kernel(
    const __half2* __restrict__ feat2,
    const unsigned short* __restrict__ es0, const int* __restrict__ off0, const int* __restrict__ deg0,
    const unsigned short* __restrict__ es1, const int* __restrict__ off1, const int* __restrict__ deg1,
    __half2* __restrict__ rst2) {
    int wid  = (blockIdx.x * blockDim.x + threadIdx.x) >> 6;
    int lane = threadIdx.x & 63;
    if (wid >= NN) return;

    float ax0 = 0.f, ay0 = 0.f, ax1 = 0.f, ay1 = 0.f;

    int d0 = deg0[wid], o0 = off0[wid];
    int e = 0;
    for (; e + 4 <= d0; e += 4) {
        int s0 = __builtin_nontemporal_load(&es0[o0 + e]);
        int s1 = __builtin_nontemporal_load(&es0[o0 + e + 1]);
        int s2 = __builtin_nontemporal_load(&es0[o0 + e + 2]);
        int s3 = __builtin_nontemporal_load(&es0[o0 + e + 3]);
        float2 v0 = __half22float2(feat2[(size_t)s0 * 64 + lane]);
        float2 v1 = __half22float2(feat2[(size_t)s1 * 64 + lane]);
        float2 v2 = __half22float2(feat2[(size_t)s2 * 64 + lane]);
        float2 v3 = __half22float2(feat2[(size_t)s3 * 64 + lane]);
        ax0 += (v0.x + v1.x) + (v2.x + v3.x);
        ay0 += (v0.y + v1.y) + (v2.y + v3.y);
    }
    if (e < d0) {                     // masked tail quad (1..3 real edges)
        int last = d0 - 1;
#pragma unroll
        for (int j = 0; j < 4; j++) {
            int ee = e + j;
            int s = __builtin_nontemporal_load(&es0[o0 + min(ee, last)]);
            float2 v = __half22float2(feat2[(size_t)s * 64 + lane]);
            float m = (ee < d0) ? 1.f : 0.f;
            ax0 = fmaf(v.x, m, ax0);
            ay0 = fmaf(v.y, m, ay0);
        }
    }

    int d1 = deg1[wid], o1 = off1[wid];
    e = 0;
    for (; e + 4 <= d1; e += 4) {
        int s0 = __builtin_nontemporal_load(&es1[o1 + e]);
        int s1 = __builtin_nontemporal_load(&es1[o1 + e + 1]);
        int s2 = __builtin_nontemporal_load(&es1[o1 + e + 2]);
        int s3 = __builtin_nontemporal_load(&es1[o1 + e + 3]);
        float2 v0 = __half22float2(feat2[(size_t)s0 * 64 + lane]);
        float2 v1 = __half22float2(feat2[(size_t)s1 * 64 + lane]);
        float2 v2 = __half22float2(feat2[(size_t)s2 * 64 + lane]);
        float2 v3 = __half22float2(feat2[(size_t)s3 * 64 + lane]);
        ax1 += (v0.x + v1.x) + (v2.x + v3.x);
        ay1 += (v0.y + v1.y) + (v2.y + v3.y);
    }
    if (e < d1) {
        int last = d1 - 1;
#pragma unroll
        for (int j = 0; j < 4; j++) {
            int ee = e + j;
            int s = __builtin_nontemporal_load(&es1[o1 + min(ee, last)]);
            float2 v = __half22float2(feat2[(size_t)s * 64 + lane]);
            float m = (ee < d1) ? 1.f : 0.f;
            ax1 = fmaf(v.x, m, ax1);
            ay1 = fmaf(v.y, m, ay1);
        }
    }

    float inv0 = 1.0f / fmaxf((float)d0, 1.0f);
    float inv1 = 1.0f / fmaxf((float)d1, 1.0f);
    float na = fmaxf((float)((d0 > 0) + (d1 > 0)), 1.0f);
    float rx = (ax0 * inv0 + ax1 * inv1) / na;
    float ry = (ay0 * inv0 + ay1 * inv1) / na;
    rst2[(size_t)wid * 64 + lane] = __floats2half2_rn(rx, ry);
}

// ---------------- node kernel: MFMA gates GEMM + LSTM epilogue ----------
__global__ __launch_bounds__(256) void node_kernel(
    const __half* __restrict__ feat_h,
    const __half* __restrict__ rst_h,
    const __half* __restrict__ WC, const float* __restrict__ bsum,
    float* __restrict__ out) {
    __shared__ __half xs[32 * 200];

    int t  = threadIdx.x;
    int nb = blockIdx.x * NPB;
    int lane = t & 63;
    int w    = t >> 6;
    int col  = lane & 15;   // A-row / C-col / B-col
    int g4   = lane >> 4;   // k-group

    f16x8 bfr[4][6];
    float bias[4];
#pragma unroll
    for (int ct = 0; ct < 4; ct++) {
        int gate = ct * 64 + w * 16 + col;
        bias[ct] = bsum[gate];
#pragma unroll
        for (int ks = 0; ks < 6; ks++)
            bfr[ct][ks] = *(const f16x8*)(WC + (size_t)gate * 192 + ks * 32 + g4 * 8);
    }

    const uint4* feat4 = (const uint4*)feat_h;
    const uint4* rst4  = (const uint4*)rst_h;
#pragma unroll
    for (int j = 0; j < 2; j++) {
        int e = t + j * 256;
        int n = e >> 4, q = e & 15;
        int gn = nb + n;
        uint4 v = make_uint4(0, 0, 0, 0);
        if (gn < NN) v = feat4[(size_t)gn * 16 + q];
        *(uint4*)(&xs[n * 200 + q * 8]) = v;
    }
    {
        int n = t >> 3, q = t & 7;
        int gn = nb + n;
        uint4 v = make_uint4(0, 0, 0, 0);
        if (gn < NN) v = rst4[(size_t)gn * 16 + q];
        *(uint4*)(&xs[n * 200 + 128 + q * 8]) = v;
    }
    __syncthreads();

    f32x4 acc[2][4];
#pragma unroll
    for (int rt = 0; rt < 2; rt++)
#pragma unroll
        for (int ct = 0; ct < 4; ct++)
            acc[rt][ct] = (f32x4){bias[ct], bias[ct], bias[ct], bias[ct]};

#pragma unroll
    for (int ks = 0; ks < 6; ks++) {
        f16x8 a0 = *(const f16x8*)(&xs[(col) * 200 + ks * 32 + g4 * 8]);
        f16x8 a1 = *(const f16x8*)(&xs[(16 + col) * 200 + ks * 32 + g4 * 8]);
#pragma unroll
        for (int ct = 0; ct < 4; ct++) {
            acc[0][ct] = __builtin_amdgcn_mfma_f32_16x16x32_f16(a0, bfr[ct][ks], acc[0][ct], 0, 0, 0);
            acc[1][ct] = __builtin_amdgcn_mfma_f32_16x16x32_f16(a1, bfr[ct][ks], acc[1][ct], 0, 0, 0);
        }
    }

    int m = w * 16 + col;
#pragma unroll
    for (int rt = 0; rt < 2; rt++) {
#pragma unroll
        for (int r = 0; r < 4; r++) {
            int nl = rt * 16 + g4 * 4 + r;
            int gn = nb + nl;
            if (gn >= NN) continue;
            float iv = sigmoidf_(acc[rt][0][r]);
            float fv = sigmoidf_(acc[rt][1][r]);
            float gv = tanhf_(acc[rt][2][r]);
            float ov = sigmoidf_(acc[rt][3][r]);
            float R  = __half2float(rst_h[(size_t)gn * 128 + 64 + m]);
            float c1 = fv * R + iv * gv;
            float h1 = ov * tanhf_(c1);
            out[(size_t)gn * 128 + m]      = h1;
            out[(size_t)gn * 128 + 64 + m] = c1;
        }
    }
}

extern "C" void kernel_launch(void* const* d_in, const int* in_sizes, int n_in,
                              void* d_out, int out_size, void* d_ws, size_t ws_size,
                              hipStream_t stream) {
    const float* feat = (const float*)d_in[0];
    const int*   src0 = (const int*)d_in[1];
    const int*   dst0 = (const int*)d_in[2];
    const int*   src1 = (const int*)d_in[3];
    const int*   dst1 = (const int*)d_in[4];
    const float* W_ih = (const float*)d_in[5];
    const float* W_hh = (const float*)d_in[6];
    const float* b_ih = (const float*)d_in[7];
    const float* b_hh = (const float*)d_in[8];
    float* out = (float*)d_out;

    // workspace layout (16B-aligned pieces)
    char* p = (char*)d_ws;
    int* bcnt = (int*)p;            p += 2 * NBKT * 4;   // zeroed
    int* off0 = (int*)p;            p += NN * 4;
    int* off1 = (int*)p;            p += NN * 4;
    int* deg0 = (int*)p;            p += NN * 4;
    int* deg1 = (int*)p;            p += NN * 4;
    unsigned* binned0 = (unsigned*)p; p += (size_t)NBKT * BKT_CAP * 4;  // 4.8 MB
    unsigned* binned1 = (unsigned*)p; p += (size_t)NBKT * BKT_CAP * 4;  // 4.8 MB
    unsigned short* es0 = (unsigned short*)p; p += (size_t)NBKT * BKT_CAP * 2;
    unsigned short* es1 = (unsigned short*)p; p += (size_t)NBKT * BKT_CAP * 2;
    __half* feat_h = (__half*)p;    p += (size_t)NN * 128 * 2;
    __half* rst_h  = (__half*)p;    p += (size_t)NN * 128 * 2;
    __half* WC     = (__half*)p;    p += (size_t)256 * 192 * 2;
    float*  bsum   = (float*)p;     p += 256 * 4;

    hipMemsetAsync(bcnt, 0, 2 * NBKT * sizeof(int), stream);

    int blocksP = (NN * 128 / 4 + 255) / 256;  // 6250
    prep_kernel<<<blocksP, 256, 0, stream>>>(feat, feat_h, W_ih, W_hh, b_ih, b_hh,
                                             WC, bsum);

    bin_kernel<<<2 * NCH, 256, 0, stream>>>(src0, dst0, src1, dst1, bcnt,
                                            binned0, binned1);

    bucket_scatter_kernel<<<2 * NBKT, 256, 0, stream>>>(binned0, binned1, bcnt,
                                                        off0, off1, deg0, deg1,
                                                        es0, es1);

    int blocksG = (NN * 64 + 255) / 256;  // 12500 (one wave per node)
    gather_kernel<<<blocksG, 256, 0, stream>>>((const __half2*)feat_h,
                                               es0, off0, deg0, es1, off1, deg1,
                                               (__half2*)rst_h);

    int blocksN = (NN + NPB - 1) / NPB;   // 1563
    node_kernel<<<blocksN, 256, 0, stream>>>(feat_h, rst_h, WC, bsum, out);
}

// Round 9
// 139.095 us; speedup vs baseline: 3.1203x; 1.2517x over previous
//
#include <hip/hip_runtime.h>
#include <hip/hip_fp16.h>
#include <cmath>

#define NN 50000
#define NE 800000
#define NPB 32
#define NBKT 196       // ceil(50000/256)
#define BKT_SHIFT 8    // 256 nodes per bucket
#define BKT_NODES 256
#define BKT_CAP 6144   // fixed region per bucket (mean ~4082, sigma ~64)
#define CHUNK 4096
#define NCH 196        // ceil(800000/4096)

using f16x8 = __attribute__((ext_vector_type(8))) _Float16;
using f32x4 = __attribute__((ext_vector_type(4))) float;

__device__ __forceinline__ float sigmoidf_(float x) {
    return 1.0f / (1.0f + __expf(-x));
}
__device__ __forceinline__ float tanhf_(float x) {
    float t = __expf(-2.0f * fabsf(x));
    float r = (1.0f - t) / (1.0f + t);
    return copysignf(r, x);
}

// ---------------- prep: feat f32->f16, WC fp16, bias, zero bcnt ---------
__global__ __launch_bounds__(256) void prep_kernel(
    const float* __restrict__ feat, __half* __restrict__ feat_h,
    const float* __restrict__ Wih, const float* __restrict__ Whh,
    const float* __restrict__ b_ih, const float* __restrict__ b_hh,
    __half* __restrict__ WC, float* __restrict__ bsum,
    int* __restrict__ bcnt) {
    int i = blockIdx.x * blockDim.x + threadIdx.x;  // 0 .. 1,599,999

    {
        const float4 v = ((const float4*)feat)[i];
        __half2 lo = __floats2half2_rn(v.x, v.y);
        __half2 hi = __floats2half2_rn(v.z, v.w);
        ((__half2*)feat_h)[2 * i]     = lo;
        ((__half2*)feat_h)[2 * i + 1] = hi;
    }
    // WC[g][0:128] = W_ih[g][:], WC[g][128:192] = W_hh[g][:]
    if (i < 256 * 128) {
        int g = i >> 7, k = i & 127;
        WC[(size_t)g * 192 + k] = __float2half(Wih[i]);
    }
    if (i < 256 * 64) {
        int g = i >> 6, k = i & 63;
        WC[(size_t)g * 192 + 128 + k] = __float2half(Whh[i]);
    }
    if (i < 256) bsum[i] = b_ih[i] + b_hh[i];
    if (i < 2 * NBKT) bcnt[i] = 0;
}

// ---------------- phase A: bin edges into fixed-stride bucket regions ---
// binned entry = (dst << 16) | src. Region for bucket b: [b*BKT_CAP, ...).
__global__ __launch_bounds__(256) void bin_kernel(
    const int* __restrict__ src0, const int* __restrict__ dst0,
    const int* __restrict__ src1, const int* __restrict__ dst1,
    int* __restrict__ bcnt,   // [2*NBKT], zeroed by prep
    unsigned* __restrict__ binned0, unsigned* __restrict__ binned1) {
    __shared__ int cnt[NBKT];
    __shared__ int base[NBKT];
    __shared__ int cur[NBKT];
    __shared__ int sdst[CHUNK];

    int x  = blockIdx.x;             // 0 .. 2*NCH-1
    int et = x >= NCH;
    int c  = et ? x - NCH : x;
    const int* src = et ? src1 : src0;
    const int* dst = et ? dst1 : dst0;
    unsigned* binned = et ? binned1 : binned0;

    int start = c * CHUNK;
    int n = min(CHUNK, NE - start);
    int tid = threadIdx.x;

    if (tid < NBKT) { cnt[tid] = 0; cur[tid] = 0; }
    __syncthreads();
    for (int i = tid; i < n; i += 256) {
        int d = dst[start + i];
        sdst[i] = d;
        atomicAdd(&cnt[d >> BKT_SHIFT], 1);
    }
    __syncthreads();
    if (tid < NBKT && cnt[tid] > 0)
        base[tid] = atomicAdd(&bcnt[et * NBKT + tid], cnt[tid]);
    __syncthreads();
    for (int i = tid; i < n; i += 256) {
        int d = sdst[i];
        int b = d >> BKT_SHIFT;
        int r = atomicAdd(&cur[b], 1);
        binned[(size_t)b * BKT_CAP + base[b] + r] =
            ((unsigned)d << 16) | (unsigned)src[start + i];
    }
}

// ---------------- phase B: per-bucket CSR finalize + es scatter ---------
// writes deg[] and off[] (off points into the bucket's fixed es region).
__global__ __launch_bounds__(256) void bucket_scatter_kernel(
    const unsigned* __restrict__ binned0, const unsigned* __restrict__ binned1,
    const int* __restrict__ bcnt,
    int* __restrict__ off0, int* __restrict__ off1,
    int* __restrict__ deg0, int* __restrict__ deg1,
    unsigned short* __restrict__ es0, unsigned short* __restrict__ es1) {
    __shared__ int lcnt[BKT_NODES];
    __shared__ int lbase[BKT_NODES];

    int g  = blockIdx.x;             // 0 .. 2*NBKT-1
    int et = g >= NBKT;
    int b  = et ? g - NBKT : g;
    const unsigned* binned = (et ? binned1 : binned0) + (size_t)b * BKT_CAP;
    int* off = et ? off1 : off0;
    int* deg = et ? deg1 : deg0;
    unsigned short* es = (et ? es1 : es0) + (size_t)b * BKT_CAP;

    int bn = bcnt[g];
    int node0 = b * BKT_NODES;
    int tid = threadIdx.x;

    lcnt[tid] = 0;
    __syncthreads();
    for (int i = tid; i < bn; i += 256) {
        unsigned u = binned[i];
        int d = (int)(u >> 16) - node0;
        atomicAdd(&lcnt[d], 1);
    }
    __syncthreads();
    int cntv = lcnt[tid];             // per-node count
    // inclusive Hillis-Steele scan, 1 element/thread
    for (int d = 1; d < BKT_NODES; d <<= 1) {
        int v = (tid >= d) ? lcnt[tid - d] : 0;
        __syncthreads();
        lcnt[tid] += v;
        __syncthreads();
    }
    int excl = lcnt[tid] - cntv;
    lbase[tid] = excl;
    int gn = node0 + tid;
    if (gn < NN) { off[gn] = b * BKT_CAP + excl; deg[gn] = cntv; }
    __syncthreads();
    for (int i = tid; i < bn; i += 256) {
        unsigned u = binned[i];
        int d = (int)(u >> 16) - node0;
        int r = atomicAdd(&lbase[d], 1);
        es[r] = (unsigned short)(u & 0xffffu);
    }
}

// ---------------- gather: wave per node, 2 rows/instr, 8 rows in flight -
// lane = (hf, c): hf = which row of the pair, c = uint2 col (4 halves).
__global__ __launch_bounds__(256) void gather_kernel(
    const uint2* __restrict__ featu,   // feat_h as uint2: 32 per 128-half row
    const unsigned short* __restrict__ es0, const int* __restrict__ off0, const int* __restrict__ deg0,
    const unsigned short* __restrict__ es1, const int* __restrict__ off1, const int* __restrict__ deg1,
    uint2* __restrict__ rstu) {
    int wid  = (blockIdx.x * blockDim.x + threadIdx.x) >> 6;
    int lane = threadIdx.x & 63;
    if (wid >= NN) return;
    int hf = lane >> 5;     // 0/1: which edge of the pair
    int c  = lane & 31;     // uint2 column

    float a0[4] = {0.f, 0.f, 0.f, 0.f};
    float a1[4] = {0.f, 0.f, 0.f, 0.f};

    int d0 = deg0[wid], o0 = off0[wid];
    int e = 0;
    for (; e + 8 <= d0; e += 8) {
        int s0 = es0[o0 + e + 0 + hf];
        int s1 = es0[o0 + e + 2 + hf];
        int s2 = es0[o0 + e + 4 + hf];
        int s3 = es0[o0 + e + 6 + hf];
        uint2 v0 = featu[(size_t)s0 * 32 + c];
        uint2 v1 = featu[(size_t)s1 * 32 + c];
        uint2 v2 = featu[(size_t)s2 * 32 + c];
        uint2 v3 = featu[(size_t)s3 * 32 + c];
#pragma unroll
        for (int k = 0; k < 1; k++) { }  // (keep loads grouped)
        {
            float2 f;
            f = __half22float2(*(__half2*)&v0.x); a0[0] += f.x; a0[1] += f.y;
            f = __half22float2(*(__half2*)&v0.y); a0[2] += f.x; a0[3] += f.y;
            f = __half22float2(*(__half2*)&v1.x); a0[0] += f.x; a0[1] += f.y;
            f = __half22float2(*(__half2*)&v1.y); a0[2] += f.x; a0[3] += f.y;
            f = __half22float2(*(__half2*)&v2.x); a0[0] += f.x; a0[1] += f.y;
            f = __half22float2(*(__half2*)&v2.y); a0[2] += f.x; a0[3] += f.y;
            f = __half22float2(*(__half2*)&v3.x); a0[0] += f.x; a0[1] += f.y;
            f = __half22float2(*(__half2*)&v3.y); a0[2] += f.x; a0[3] += f.y;
        }
    }
    if (e < d0) {
        int last = d0 - 1;
#pragma unroll
        for (int j = 0; j < 4; j++) {
            int ee = e + 2 * j + hf;
            int s = es0[o0 + min(ee, last)];
            uint2 v = featu[(size_t)s * 32 + c];
            float m = (ee < d0) ? 1.f : 0.f;
            float2 f;
            f = __half22float2(*(__half2*)&v.x); a0[0] = fmaf(f.x, m, a0[0]); a0[1] = fmaf(f.y, m, a0[1]);
            f = __half22float2(*(__half2*)&v.y); a0[2] = fmaf(f.x, m, a0[2]); a0[3] = fmaf(f.y, m, a0[3]);
        }
    }

    int d1 = deg1[wid], o1 = off1[wid];
    e = 0;
    for (; e + 8 <= d1; e += 8) {
        int s0 = es1[o1 + e + 0 + hf];
        int s1 = es1[o1 + e + 2 + hf];
        int s2 = es1[o1 + e + 4 + hf];
        int s3 = es1[o1 + e + 6 + hf];
        uint2 v0 = featu[(size_t)s0 * 32 + c];
        uint2 v1 = featu[(size_t)s1 * 32 + c];
        uint2 v2 = featu[(size_t)s2 * 32 + c];
        uint2 v3 = featu[(size_t)s3 * 32 + c];
        {
            float2 f;
            f = __half22float2(*(__half2*)&v0.x); a1[0] += f.x; a1[1] += f.y;
            f = __half22float2(*(__half2*)&v0.y); a1[2] += f.x; a1[3] += f.y;
            f = __half22float2(*(__half2*)&v1.x); a1[0] += f.x; a1[1] += f.y;
            f = __half22float2(*(__half2*)&v1.y); a1[2] += f.x; a1[3] += f.y;
            f = __half22float2(*(__half2*)&v2.x); a1[0] += f.x; a1[1] += f.y;
            f = __half22float2(*(__half2*)&v2.y); a1[2] += f.x; a1[3] += f.y;
            f = __half22float2(*(__half2*)&v3.x); a1[0] += f.x; a1[1] += f.y;
            f = __half22float2(*(__half2*)&v3.y); a1[2] += f.x; a1[3] += f.y;
        }
    }
    if (e < d1) {
        int last = d1 - 1;
#pragma unroll
        for (int j = 0; j < 4; j++) {
            int ee = e + 2 * j + hf;
            int s = es1[o1 + min(ee, last)];
            uint2 v = featu[(size_t)s * 32 + c];
            float m = (ee < d1) ? 1.f : 0.f;
            float2 f;
            f = __half22float2(*(__half2*)&v.x); a1[0] = fmaf(f.x, m, a1[0]); a1[1] = fmaf(f.y, m, a1[1]);
            f = __half22float2(*(__half2*)&v.y); a1[2] = fmaf(f.x, m, a1[2]); a1[3] = fmaf(f.y, m, a1[3]);
        }
    }

    // combine the pair halves (lane ^ 32)
#pragma unroll
    for (int k = 0; k < 4; k++) {
        a0[k] += __shfl_xor(a0[k], 32, 64);
        a1[k] += __shfl_xor(a1[k], 32, 64);
    }

    if (hf == 0) {
        float inv0 = 1.0f / fmaxf((float)d0, 1.0f);
        float inv1 = 1.0f / fmaxf((float)d1, 1.0f);
        float na = fmaxf((float)((d0 > 0) + (d1 > 0)), 1.0f);
        float r0 = (a0[0] * inv0 + a1[0] * inv1) / na;
        float r1 = (a0[1] * inv0 + a1[1] * inv1) / na;
        float r2 = (a0[2] * inv0 + a1[2] * inv1) / na;
        float r3 = (a0[3] * inv0 + a1[3] * inv1) / na;
        __half2 h01 = __floats2half2_rn(r0, r1);
        __half2 h23 = __floats2half2_rn(r2, r3);
        uint2 o;
        o.x = *(unsigned*)&h01;
        o.y = *(unsigned*)&h23;
        rstu[(size_t)wid * 32 + c] = o;
    }
}

// ---------------- node kernel: MFMA gates GEMM + LSTM epilogue ----------
__global__ __launch_bounds__(256) void node_kernel(
    const __half* __restrict__ feat_h,
    const __half* __restrict__ rst_h,
    const __half* __restrict__ WC, const float* __restrict__ bsum,
    float* __restrict__ out) {
    __shared__ __half xs[32 * 200];

    int t  = threadIdx.x;
    int nb = blockIdx.x * NPB;
    int lane = t & 63;
    int w    = t >> 6;
    int col  = lane & 15;   // A-row / C-col / B-col
    int g4   = lane >> 4;   // k-group

    f16x8 bfr[4][6];
    float bias[4];
#pragma unroll
    for (int ct = 0; ct < 4; ct++) {
        int gate = ct * 64 + w * 16 + col;
        bias[ct] = bsum[gate];
#pragma unroll
        for (int ks = 0; ks < 6; ks++)
            bfr[ct][ks] = *(const f16x8*)(WC + (size_t)gate * 192 + ks * 32 + g4 * 8);
    }

    const uint4* feat4 = (const uint4*)feat_h;
    const uint4* rst4  = (const uint4*)rst_h;
#pragma unroll
    for (int j = 0; j < 2; j++) {
        int e = t + j * 256;
        int n = e >> 4, q = e & 15;
        int gn = nb + n;
        uint4 v = make_uint4(0, 0, 0, 0);
        if (gn < NN) v = feat4[(size_t)gn * 16 + q];
        *(uint4*)(&xs[n * 200 + q * 8]) = v;
    }
    {
        int n = t >> 3, q = t & 7;
        int gn = nb + n;
        uint4 v = make_uint4(0, 0, 0, 0);
        if (gn < NN) v = rst4[(size_t)gn * 16 + q];
        *(uint4*)(&xs[n * 200 + 128 + q * 8]) = v;
    }
    __syncthreads();

    f32x4 acc[2][4];
#pragma unroll
    for (int rt = 0; rt < 2; rt++)
#pragma unroll
        for (int ct = 0; ct < 4; ct++)
            acc[rt][ct] = (f32x4){bias[ct], bias[ct], bias[ct], bias[ct]};

#pragma unroll
    for (int ks = 0; ks < 6; ks++) {
        f16x8 a0 = *(const f16x8*)(&xs[(col) * 200 + ks * 32 + g4 * 8]);
        f16x8 a1 = *(const f16x8*)(&xs[(16 + col) * 200 + ks * 32 + g4 * 8]);
#pragma unroll
        for (int ct = 0; ct < 4; ct++) {
            acc[0][ct] = __builtin_amdgcn_mfma_f32_16x16x32_f16(a0, bfr[ct][ks], acc[0][ct], 0, 0, 0);
            acc[1][ct] = __builtin_amdgcn_mfma_f32_16x16x32_f16(a1, bfr[ct][ks], acc[1][ct], 0, 0, 0);
        }
    }

    int m = w * 16 + col;
#pragma unroll
    for (int rt = 0; rt < 2; rt++) {
#pragma unroll
        for (int r = 0; r < 4; r++) {
            int nl = rt * 16 + g4 * 4 + r;
            int gn = nb + nl;
            if (gn >= NN) continue;
            float iv = sigmoidf_(acc[rt][0][r]);
            float fv = sigmoidf_(acc[rt][1][r]);
            float gv = tanhf_(acc[rt][2][r]);
            float ov = sigmoidf_(acc[rt][3][r]);
            float R  = __half2float(rst_h[(size_t)gn * 128 + 64 + m]);
            float c1 = fv * R + iv * gv;
            float h1 = ov * tanhf_(c1);
            out[(size_t)gn * 128 + m]      = h1;
            out[(size_t)gn * 128 + 64 + m] = c1;
        }
    }
}

extern "C" void kernel_launch(void* const* d_in, const int* in_sizes, int n_in,
                              void* d_out, int out_size, void* d_ws, size_t ws_size,
                              hipStream_t stream) {
    const float* feat = (const float*)d_in[0];
    const int*   src0 = (const int*)d_in[1];
    const int*   dst0 = (const int*)d_in[2];
    const int*   src1 = (const int*)d_in[3];
    const int*   dst1 = (const int*)d_in[4];
    const float* W_ih = (const float*)d_in[5];
    const float* W_hh = (const float*)d_in[6];
    const float* b_ih = (const float*)d_in[7];
    const float* b_hh = (const float*)d_in[8];
    float* out = (float*)d_out;

    // workspace layout (16B-aligned pieces)
    char* p = (char*)d_ws;
    int* bcnt = (int*)p;            p += 2 * NBKT * 4;   // zeroed by prep
    int* off0 = (int*)p;            p += NN * 4;
    int* off1 = (int*)p;            p += NN * 4;
    int* deg0 = (int*)p;            p += NN * 4;
    int* deg1 = (int*)p;            p += NN * 4;
    unsigned* binned0 = (unsigned*)p; p += (size_t)NBKT * BKT_CAP * 4;  // 4.8 MB
    unsigned* binned1 = (unsigned*)p; p += (size_t)NBKT * BKT_CAP * 4;  // 4.8 MB
    unsigned short* es0 = (unsigned short*)p; p += (size_t)NBKT * BKT_CAP * 2;
    unsigned short* es1 = (unsigned short*)p; p += (size_t)NBKT * BKT_CAP * 2;
    __half* feat_h = (__half*)p;    p += (size_t)NN * 128 * 2;
    __half* rst_h  = (__half*)p;    p += (size_t)NN * 128 * 2;
    __half* WC     = (__half*)p;    p += (size_t)256 * 192 * 2;
    float*  bsum   = (float*)p;     p += 256 * 4;

    int blocksP = (NN * 128 / 4 + 255) / 256;  // 6250
    prep_kernel<<<blocksP, 256, 0, stream>>>(feat, feat_h, W_ih, W_hh, b_ih, b_hh,
                                             WC, bsum, bcnt);

    bin_kernel<<<2 * NCH, 256, 0, stream>>>(src0, dst0, src1, dst1, bcnt,
                                            binned0, binned1);

    bucket_scatter_kernel<<<2 * NBKT, 256, 0, stream>>>(binned0, binned1, bcnt,
                                                        off0, off1, deg0, deg1,
                                                        es0, es1);

    int blocksG = (NN * 64 + 255) / 256;  // 12500 (one wave per node)
    gather_kernel<<<blocksG, 256, 0, stream>>>((const uint2*)feat_h,
                                               es0, off0, deg0, es1, off1, deg1,
                                               (uint2*)rst_h);

    int blocksN = (NN + NPB - 1) / NPB;   // 1563
    node_kernel<<<blocksN, 256, 0, stream>>>(feat_h, rst_h, WC, bsum, out);
}